// Round 1
// baseline (464.269 us; speedup 1.0000x reference)
//
#include <hip/hip_runtime.h>

#define N_DIM 64
#define C_DIM 16
#define J_DIM 25
#define T_DIM 120
#define O_DIM 64
#define SIG   306      // 17 + 17*17
#define TCHUNK 32
#define YPAD  307      // odd stride -> conflict-free column reads

__global__ __launch_bounds__(256, 4) void sig_kernel(
    const float* __restrict__ x, const float* __restrict__ W,
    const float* __restrict__ bias, float* __restrict__ out)
{
    __shared__ float xs[C_DIM][T_DIM];     // 7.68 KB
    __shared__ float ys[TCHUNK][YPAD];     // 39.3 KB

    const int tid = threadIdx.x;
    const int bid = blockIdx.x;
    const int chunk = bid & 3;                 // 4 chunks of 32 t's (last has 24)
    const int j = (bid >> 2) % J_DIM;
    const int n = bid / (4 * J_DIM);
    const int t0 = chunk * TCHUNK;

    // ---- stage x[n, :, j, :] ----
    for (int i = tid; i < C_DIM * T_DIM; i += 256) {
        int k = i / T_DIM, t = i % T_DIM;
        xs[k][t] = x[((size_t)(n * C_DIM + k) * J_DIM + j) * T_DIM + t];
    }
    __syncthreads();

    // ---- phase 1: signature features into ys ----
    {
        const int tl = tid >> 3;    // 0..31 : local t
        const int r  = tid & 7;     // 0..7  : row group
        const int t  = t0 + tl;
        if (t < T_DIM) {
            const int start = max(t - 2, 0);
            const int end   = min(t + 3, T_DIM);
            const float invLm1 = 1.0f / (float)(end - start - 1);
            int   pc[5];
            float pt[5];
            #pragma unroll
            for (int w = 0; w < 5; ++w) {
                int p = t + w - 2;
                pc[w] = min(max(p, 0), T_DIM - 1);
                pt[w] = (float)(pc[w] - start) * invLm1;
            }
            // rows a = r, r+8, (r==0 also 16)
            for (int a = r; a < 17; a += 8) {
                const int am = (a < 16) ? a : 0;
                float pa[5];
                #pragma unroll
                for (int w = 0; w < 5; ++w) {
                    float v = xs[am][pc[w]];
                    pa[w] = (a < 16) ? v : pt[w];
                }
                float m[5];
                m[0] = 0.5f * pa[0];
                #pragma unroll
                for (int w = 1; w < 5; ++w) m[w] = 0.5f * (pa[w - 1] + pa[w]);
                ys[tl][a] = pa[4];                    // S1 = last path point
                for (int bc = 0; bc < 17; ++bc) {
                    const int bm = (bc < 16) ? bc : 0;
                    float acc = 0.f, prev = 0.f;
                    #pragma unroll
                    for (int w = 0; w < 5; ++w) {
                        float pv = xs[bm][pc[w]];
                        float pb = (bc < 16) ? pv : pt[w];
                        acc += m[w] * (pb - prev);   // m_w[a] * v_w[b]
                        prev = pb;
                    }
                    ys[tl][17 + a * 17 + bc] = acc;
                }
            }
        }
    }
    __syncthreads();

    // ---- phase 2: y (32x306) @ W (306x64) + b, transposed store ----
    {
        const int tl = tid & 31;    // local t
        const int og = tid >> 5;    // 0..7 : group of 8 outputs
        const int t  = t0 + tl;
        if (t < T_DIM) {
            float acc[8];
            #pragma unroll
            for (int oi = 0; oi < 8; ++oi) acc[oi] = bias[og * 8 + oi];
            const float4* W4 = (const float4*)W;
            #pragma unroll 2
            for (int s = 0; s < SIG; ++s) {
                float  yv = ys[tl][s];
                float4 w0 = W4[s * 16 + og * 2];
                float4 w1 = W4[s * 16 + og * 2 + 1];
                acc[0] += yv * w0.x; acc[1] += yv * w0.y;
                acc[2] += yv * w0.z; acc[3] += yv * w0.w;
                acc[4] += yv * w1.x; acc[5] += yv * w1.y;
                acc[6] += yv * w1.z; acc[7] += yv * w1.w;
            }
            size_t ob = ((size_t)(n * O_DIM + og * 8) * J_DIM + j) * T_DIM + t;
            #pragma unroll
            for (int oi = 0; oi < 8; ++oi)
                out[ob + (size_t)oi * (J_DIM * T_DIM)] = acc[oi];
        }
    }
}

extern "C" void kernel_launch(void* const* d_in, const int* in_sizes, int n_in,
                              void* d_out, int out_size, void* d_ws, size_t ws_size,
                              hipStream_t stream) {
    const float* x = (const float*)d_in[0];
    const float* W = (const float*)d_in[1];
    const float* b = (const float*)d_in[2];
    float* out = (float*)d_out;
    const int blocks = N_DIM * J_DIM * 4;   // 6400
    sig_kernel<<<blocks, 256, 0, stream>>>(x, W, b, out);
}

// Round 2
// 69.296 us; speedup vs baseline: 6.6998x; 6.6998x over previous
//
#include <hip/hip_runtime.h>

#define N_DIM 64
#define C_DIM 16
#define J_DIM 25
#define T_DIM 120
#define O_DIM 64
#define SIG   306        // 17 + 17*17
#define KPAD  328        // row stride in bf16 elems; 656 B = 41*16 -> aligned b128, 2-way banks
#define KITER 10         // 10 * 32 = 320 >= SIG

typedef __attribute__((ext_vector_type(8))) short bf16x8;
typedef __attribute__((ext_vector_type(4))) float f32x4;

__device__ __forceinline__ unsigned short f2bf(float f) {
    union { float f; unsigned u; } v; v.f = f;
    unsigned r = v.u + 0x7FFFu + ((v.u >> 16) & 1u);
    return (unsigned short)(r >> 16);
}

// ---- kernel 1: W (306x64 f32, k-major) -> Wf (64 rows x 328 k, bf16, zero-padded) ----
__global__ void wprep(const float* __restrict__ W, unsigned short* __restrict__ Wf) {
    int i = blockIdx.x * 256 + threadIdx.x;       // over 64 * 41 groups of 8 k
    if (i >= O_DIM * (KPAD / 8)) return;
    int n = i / (KPAD / 8);
    int k0 = (i % (KPAD / 8)) * 8;
    unsigned short v[8];
    #pragma unroll
    for (int u = 0; u < 8; ++u) {
        int k = k0 + u;
        v[u] = f2bf((k < SIG) ? W[k * O_DIM + n] : 0.0f);
    }
    *(uint4*)(Wf + n * KPAD + k0) = *(uint4*)v;
}

// ---- kernel 2: block = (n, j, T-half of 60) ----
__global__ __launch_bounds__(256, 3) void sig_mfma(
    const float* __restrict__ x, const unsigned short* __restrict__ Wf,
    const float* __restrict__ bias, float* __restrict__ out)
{
    __shared__ float xs[C_DIM][T_DIM];            // 7680 B
    __shared__ unsigned short ys[64 * KPAD];      // 41984 B

    const int tid = threadIdx.x;
    const int bid = blockIdx.x;
    const int half = bid & 1;
    const int j = (bid >> 1) % J_DIM;
    const int n = bid / (2 * J_DIM);
    const int t0 = half * 60;

    // zero ys (rows 60-63 and k>=306 must be zero for the padded MFMA reads)
    {
        uint4* y4 = (uint4*)ys;
        const int tot = 64 * KPAD * 2 / 16;       // 2624
        for (int i = tid; i < tot; i += 256) y4[i] = uint4{0, 0, 0, 0};
    }
    // stage xs = x[n, :, j, :]
    for (int i = tid; i < C_DIM * T_DIM; i += 256) {
        int c = i / T_DIM, t = i % T_DIM;
        xs[c][t] = x[((size_t)(n * C_DIM + c) * J_DIM + j) * T_DIM + t];
    }
    __syncthreads();

    // ---- phase 1: signature features -> ys (bf16) ----
    if (tid < 240) {
        const int tl = tid % 60;                  // consecutive lanes -> consecutive t
        const int quad = tid / 60;                // a-rows quad*4 .. quad*4+4 (overlaps benign)
        const int t = t0 + tl;
        const int start = max(t - 2, 0);
        const int end = min(t + 3, T_DIM);
        const float invLm1 = 1.0f / (float)(end - start - 1);
        int pc[5]; float pt[5];
        #pragma unroll
        for (int w = 0; w < 5; ++w) {
            int p = t - 2 + w;
            pc[w] = min(max(p, 0), T_DIM - 1);
            pt[w] = (float)(pc[w] - start) * invLm1;
        }
        const int a0 = quad * 4;
        float m[5][5];
        #pragma unroll
        for (int r = 0; r < 5; ++r) {
            const int a = a0 + r;
            float pa[5];
            #pragma unroll
            for (int w = 0; w < 5; ++w)
                pa[w] = (a < 16) ? xs[a < 16 ? a : 0][pc[w]] : pt[w];
            m[r][0] = 0.5f * pa[0];
            #pragma unroll
            for (int w = 1; w < 5; ++w) m[r][w] = 0.5f * (pa[w - 1] + pa[w]);
            ys[tl * KPAD + a] = f2bf(pa[4]);      // S1 = last path point
        }
        for (int b = 0; b < 17; ++b) {
            float pb[5], dv[5];
            #pragma unroll
            for (int w = 0; w < 5; ++w)
                pb[w] = (b < 16) ? xs[b < 16 ? b : 0][pc[w]] : pt[w];
            dv[0] = pb[0];
            #pragma unroll
            for (int w = 1; w < 5; ++w) dv[w] = pb[w] - pb[w - 1];
            #pragma unroll
            for (int r = 0; r < 5; ++r) {
                float acc = 0.0f;
                #pragma unroll
                for (int w = 0; w < 5; ++w) acc = fmaf(m[r][w], dv[w], acc);
                ys[tl * KPAD + 17 + (a0 + r) * 17 + b] = f2bf(acc);
            }
        }
    }
    __syncthreads();

    // ---- phase 2: (64 x 320) @ (320 x 64) via mfma_f32_16x16x32_bf16 ----
    {
        const int wave = tid >> 6;                // row-tile
        const int lane = tid & 63;
        const int l15 = lane & 15;
        const int l4 = lane >> 4;

        f32x4 acc[4];
        #pragma unroll
        for (int c = 0; c < 4; ++c) {
            float bv = bias[c * 16 + l15];
            acc[c] = f32x4{bv, bv, bv, bv};
        }
        const unsigned short* abase = ys + (wave * 16 + l15) * KPAD + l4 * 8;
        const unsigned short* bbase = Wf + l15 * KPAD + l4 * 8;
        #pragma unroll
        for (int kk = 0; kk < KITER; ++kk) {
            bf16x8 af = *(const bf16x8*)(abase + kk * 32);
            #pragma unroll
            for (int c = 0; c < 4; ++c) {
                bf16x8 bfr = *(const bf16x8*)(bbase + c * 16 * KPAD + kk * 32);
                acc[c] = __builtin_amdgcn_mfma_f32_16x16x32_bf16(af, bfr, acc[c], 0, 0, 0);
            }
        }
        // epilogue: row = (lane>>4)*4 + reg  -> 4 consecutive t; col = lane&15 -> o
        const int tlb = wave * 16 + l4 * 4;
        if (tlb < 60) {
            #pragma unroll
            for (int c = 0; c < 4; ++c) {
                int o = c * 16 + l15;
                float* op = out + ((size_t)(n * O_DIM + o) * J_DIM + j) * T_DIM + t0 + tlb;
                *(f32x4*)op = acc[c];
            }
        }
    }
}

extern "C" void kernel_launch(void* const* d_in, const int* in_sizes, int n_in,
                              void* d_out, int out_size, void* d_ws, size_t ws_size,
                              hipStream_t stream) {
    const float* x = (const float*)d_in[0];
    const float* W = (const float*)d_in[1];
    const float* b = (const float*)d_in[2];
    float* out = (float*)d_out;
    unsigned short* Wf = (unsigned short*)d_ws;   // 64*328*2 = 41984 B

    wprep<<<(O_DIM * (KPAD / 8) + 255) / 256, 256, 0, stream>>>(W, Wf);
    sig_mfma<<<N_DIM * J_DIM * 2, 256, 0, stream>>>(x, Wf, b, out);
}